// Round 1
// 934.429 us; speedup vs baseline: 1.2668x; 1.2668x over previous
//
#include <hip/hip_runtime.h>
#include <hip/hip_bf16.h>

typedef __bf16 bf16_t;
typedef __bf16 bf16x8 __attribute__((ext_vector_type(8)));
typedef float f32x4 __attribute__((ext_vector_type(4)));

#define MFMA16(A, B, C) __builtin_amdgcn_mfma_f32_16x16x32_bf16(A, B, C, 0, 0, 0)

// Async global->LDS, 16B per lane. LDS dest is wave-uniform base + lane*16.
#define GLOAD_LDS16(gp, lp)                                           \
    __builtin_amdgcn_global_load_lds(                                 \
        (const __attribute__((address_space(1))) void*)(gp),          \
        (__attribute__((address_space(3))) void*)(lp), 16, 0, 0)

// ---------------------------------------------------------------------------
// fp32 -> bf16 elementwise convert, 8 elems/thread, grid-stride.
// ---------------------------------------------------------------------------
__global__ __launch_bounds__(256)
void cvt_f32_bf16(const float* __restrict__ src, bf16_t* __restrict__ dst, int n8)
{
    int stride = gridDim.x * 256;
    for (int i = blockIdx.x * 256 + threadIdx.x; i < n8; i += stride) {
        const float4 f0 = *(const float4*)(src + (size_t)i * 8);
        const float4 f1 = *(const float4*)(src + (size_t)i * 8 + 4);
        bf16x8 v = {(bf16_t)f0.x, (bf16_t)f0.y, (bf16_t)f0.z, (bf16_t)f0.w,
                    (bf16_t)f1.x, (bf16_t)f1.y, (bf16_t)f1.z, (bf16_t)f1.w};
        *(bf16x8*)(dst + (size_t)i * 8) = v;
    }
}

// ---------------------------------------------------------------------------
// GEMM: C[M,N] = A[M,K] @ W[N,K]^T + bias[N]. A, W bf16; fp32 accum.
// m97 structure: 128x128 tile, BK=32, linear LDS [128][32], staging via
// global_load_lds width=16, 4 waves 2x2, each 64x64 (4x4 16x16x32 frags).
// ---------------------------------------------------------------------------
template <typename OT>
__global__ __launch_bounds__(256)
void gemm_bt_lds(const bf16_t* __restrict__ A, const bf16_t* __restrict__ W,
                 const float* __restrict__ bias, OT* __restrict__ C,
                 int M, int N, int K)
{
    __shared__ __align__(16) bf16_t lds_a[128 * 32];
    __shared__ __align__(16) bf16_t lds_b[128 * 32];

    const int tid  = threadIdx.x;
    const int wave = tid >> 6;
    const int lane = tid & 63;
    const int l15  = lane & 15;
    const int quad = lane >> 4;
    const int wm   = (wave >> 1) * 64;
    const int wn   = (wave & 1) * 64;

    const int bm = blockIdx.x * 128;
    const int bn = blockIdx.y * 128;

    // Staging geometry: wave w owns rows [w*32, w*32+32), two 16-row chunks.
    // Lane l covers row srow = w*32 + l/4 (+16 for chunk 1), col (l&3)*8.
    const int srow = wave * 32 + (lane >> 2);
    const int scol = (lane & 3) * 8;

    const bf16_t* Ab = A + (size_t)(bm + srow) * K + scol;
    const bf16_t* Wb = W + (size_t)(bn + srow) * K + scol;
    // Wave-uniform LDS chunk bases (16 rows * 64B = 1024B per chunk).
    bf16_t* la0 = &lds_a[wave * 32 * 32];
    bf16_t* lb0 = &lds_b[wave * 32 * 32];

    f32x4 acc[4][4] = {};

    for (int k0 = 0; k0 < K; k0 += 32) {
        GLOAD_LDS16(Ab + k0,          la0);
        GLOAD_LDS16(Ab + k0 + 16 * K, la0 + 16 * 32);
        GLOAD_LDS16(Wb + k0,          lb0);
        GLOAD_LDS16(Wb + k0 + 16 * K, lb0 + 16 * 32);
        __syncthreads();  // compiler drains vmcnt before s_barrier

        bf16x8 af[4], bfr[4];
        for (int i = 0; i < 4; ++i)
            af[i] = *(const bf16x8*)&lds_a[(wm + i * 16 + l15) * 32 + quad * 8];
        for (int j = 0; j < 4; ++j)
            bfr[j] = *(const bf16x8*)&lds_b[(wn + j * 16 + l15) * 32 + quad * 8];
        for (int i = 0; i < 4; ++i)
            for (int j = 0; j < 4; ++j)
                acc[i][j] = MFMA16(af[i], bfr[j], acc[i][j]);
        __syncthreads();
    }

    for (int i = 0; i < 4; ++i) {
        int mrow = bm + wm + i * 16 + quad * 4;
        for (int j = 0; j < 4; ++j) {
            int ncol = bn + wn + j * 16 + l15;
            float bval = bias[ncol];
            for (int r = 0; r < 4; ++r) {
                float v = acc[i][j][r] + bval;
                if constexpr (__is_same(OT, float))
                    C[(size_t)(mrow + r) * N + ncol] = v;
                else
                    C[(size_t)(mrow + r) * N + ncol] = (bf16_t)v;
            }
        }
    }
}

// ---------------------------------------------------------------------------
// RoPE in-place on Q and K (bf16 ws), layout [B*S, H*Dh], pairs (j, j+64).
// ---------------------------------------------------------------------------
__global__ __launch_bounds__(256)
void rope_kernel(bf16_t* __restrict__ Q, bf16_t* __restrict__ Kk)
{
    size_t idx = (size_t)blockIdx.x * 256 + threadIdx.x;
    int j = (int)(idx & 63);
    size_t rest = idx >> 6;
    int h = (int)(rest & 15);
    size_t row = rest >> 4;
    int s = (int)(row & 2047);

    float inv = __expf(-(float)j * 0.14391156831212787f);  // ln(10000)/64
    float ang = (float)s * inv;
    float sn, cs;
    sincosf(ang, &sn, &cs);

    size_t base = row * 2048 + (size_t)h * 128 + j;
    float q0 = (float)Q[base], q1 = (float)Q[base + 64];
    Q[base]      = (bf16_t)(q0 * cs - q1 * sn);
    Q[base + 64] = (bf16_t)(q1 * cs + q0 * sn);
    float k0 = (float)Kk[base], k1 = (float)Kk[base + 64];
    Kk[base]      = (bf16_t)(k0 * cs - k1 * sn);
    Kk[base + 64] = (bf16_t)(k1 * cs + k0 * sn);
}

// ---------------------------------------------------------------------------
// Transpose V [B,S,H*Dh] -> Vt [B,H,Dh,S]  (bf16)
// ---------------------------------------------------------------------------
__global__ __launch_bounds__(256)
void transpose_v(const bf16_t* __restrict__ V, bf16_t* __restrict__ Vt)
{
    __shared__ __align__(16) bf16_t tile[64][72];
    int bh = blockIdx.z;
    int b = bh >> 4, h = bh & 15;
    int t0 = blockIdx.x * 64;
    int d0 = blockIdx.y * 64;
    int tid = threadIdx.x;

    for (int i = 0; i < 2; ++i) {
        int c = tid + i * 256;
        int row = c >> 3, col = (c & 7) * 8;
        *(uint4*)&tile[row][col] =
            *(const uint4*)&V[((size_t)(b * 2048 + t0 + row)) * 2048 + h * 128 + d0 + col];
    }
    __syncthreads();
    for (int i = 0; i < 2; ++i) {
        int c = tid + i * 256;
        int drow = c >> 3, tcol = (c & 7) * 8;
        __align__(16) bf16_t tmp[8];
        for (int j = 0; j < 8; ++j) tmp[j] = tile[tcol + j][drow];
        *(uint4*)&Vt[((size_t)((b * 16 + h) * 128 + d0 + drow)) * 2048 + t0 + tcol] =
            *(uint4*)tmp;
    }
}

// ---------------------------------------------------------------------------
// Flash attention, shuffle-free softmax (all cross-lane via LDS + barriers).
// ---------------------------------------------------------------------------
__global__ __launch_bounds__(256)
void flash_attn(const bf16_t* __restrict__ Q, const bf16_t* __restrict__ Kg,
                const bf16_t* __restrict__ Vt, bf16_t* __restrict__ Ctx)
{
    constexpr int S = 2048, H = 16, Dh = 128, D = 2048;
    constexpr float scale = 0.08838834764831845f;  // 1/sqrt(128)

    __shared__ __align__(16) bf16_t q_lds[64][136];
    __shared__ __align__(16) bf16_t k_lds[32][136];
    __shared__ __align__(16) bf16_t vt_lds[128][40];
    __shared__ float s_lds[4][16][33];
    __shared__ float red_max[4][4][16];
    __shared__ float red_sum[4][4][16];
    __shared__ float alpha_lds[4][16];
    __shared__ float lfin_lds[4][16];

    const int bh = blockIdx.y;
    const int b = bh >> 4, h = bh & 15;
    const int q0 = blockIdx.x * 64;
    const int tid = threadIdx.x, wave = tid >> 6, lane = tid & 63;
    const int l15 = lane & 15, quad = lane >> 4;

    const bf16_t* Qh  = Q  + ((size_t)b * S) * D + h * Dh;
    const bf16_t* Kh  = Kg + ((size_t)b * S) * D + h * Dh;
    const bf16_t* Vth = Vt + ((size_t)(b * H + h)) * Dh * S;

    for (int i = 0; i < 4; ++i) {
        int c = tid + i * 256;
        int row = c >> 4, col = (c & 15) * 8;
        *(uint4*)&q_lds[row][col] = *(const uint4*)&Qh[(size_t)(q0 + row) * D + col];
    }
    __syncthreads();

    bf16x8 aq[4];
    for (int ks = 0; ks < 4; ++ks)
        aq[ks] = *(const bf16x8*)&q_lds[wave * 16 + l15][ks * 32 + quad * 8];

    float m_i = -30000.0f, l_i = 0.0f;
    f32x4 O[8] = {};

    for (int kt = 0; kt < S / 32; ++kt) {
        for (int i = 0; i < 2; ++i) {
            int c = tid + i * 256;
            int row = c >> 4, col = (c & 15) * 8;
            *(uint4*)&k_lds[row][col] =
                *(const uint4*)&Kh[(size_t)(kt * 32 + row) * D + col];
        }
        for (int i = 0; i < 2; ++i) {
            int c = tid + i * 256;
            int row = c >> 2, col = (c & 3) * 8;
            *(uint4*)&vt_lds[row][col] =
                *(const uint4*)&Vth[(size_t)row * S + kt * 32 + col];
        }
        __syncthreads();

        f32x4 sf0 = {}, sf1 = {};
        for (int ks = 0; ks < 4; ++ks) {
            bf16x8 b0 = *(const bf16x8*)&k_lds[l15][ks * 32 + quad * 8];
            bf16x8 b1 = *(const bf16x8*)&k_lds[16 + l15][ks * 32 + quad * 8];
            sf0 = MFMA16(aq[ks], b0, sf0);
            sf1 = MFMA16(aq[ks], b1, sf1);
        }
        for (int r = 0; r < 4; ++r) {
            s_lds[wave][quad * 4 + r][l15]      = sf0[r] * scale;
            s_lds[wave][quad * 4 + r][16 + l15] = sf1[r] * scale;
        }
        __syncthreads();

        float sv[8];
        float pm = -30000.0f;
        for (int j = 0; j < 8; ++j) {
            sv[j] = s_lds[wave][l15][quad * 8 + j];
            pm = fmaxf(pm, sv[j]);
        }
        red_max[wave][quad][l15] = pm;
        __syncthreads();

        float mx = fmaxf(fmaxf(red_max[wave][0][l15], red_max[wave][1][l15]),
                         fmaxf(red_max[wave][2][l15], red_max[wave][3][l15]));
        float mnew  = fmaxf(m_i, mx);
        float alpha = __expf(m_i - mnew);

        bf16x8 ap;
        float ps = 0.f;
        for (int j = 0; j < 8; ++j) {
            bf16_t pb = (bf16_t)__expf(sv[j] - mnew);
            ap[j] = pb;
            ps += (float)pb;
        }
        red_sum[wave][quad][l15] = ps;
        alpha_lds[wave][l15] = alpha;
        __syncthreads();

        float lsum = red_sum[wave][0][l15] + red_sum[wave][1][l15]
                   + red_sum[wave][2][l15] + red_sum[wave][3][l15];
        l_i = l_i * alpha + lsum;
        m_i = mnew;

        float a0 = alpha_lds[wave][quad * 4 + 0];
        float a1 = alpha_lds[wave][quad * 4 + 1];
        float a2 = alpha_lds[wave][quad * 4 + 2];
        float a3 = alpha_lds[wave][quad * 4 + 3];
        for (int j = 0; j < 8; ++j) {
            O[j][0] *= a0; O[j][1] *= a1; O[j][2] *= a2; O[j][3] *= a3;
        }

        for (int j = 0; j < 8; ++j) {
            bf16x8 bv = *(const bf16x8*)&vt_lds[j * 16 + l15][quad * 8];
            O[j] = MFMA16(ap, bv, O[j]);
        }
        __syncthreads();
    }

    lfin_lds[wave][l15] = l_i;
    __syncthreads();

    float linv[4];
    for (int r = 0; r < 4; ++r)
        linv[r] = 1.0f / lfin_lds[wave][quad * 4 + r];

    for (int r = 0; r < 4; ++r) {
        size_t row = q0 + wave * 16 + quad * 4 + r;
        for (int j = 0; j < 8; ++j)
            Ctx[((size_t)b * S + row) * D + h * Dh + j * 16 + l15] =
                (bf16_t)(O[j][r] * linv[r]);
    }
}

// ---------------------------------------------------------------------------
extern "C" void kernel_launch(void* const* d_in, const int* in_sizes, int n_in,
                              void* d_out, int out_size, void* d_ws, size_t ws_size,
                              hipStream_t stream)
{
    const float* x  = (const float*)d_in[0];
    const float* wq = (const float*)d_in[1];
    const float* bq = (const float*)d_in[2];
    const float* wk = (const float*)d_in[3];
    const float* bk = (const float*)d_in[4];
    const float* wv = (const float*)d_in[5];
    const float* bv = (const float*)d_in[6];
    const float* wo = (const float*)d_in[7];
    const float* bo = (const float*)d_in[8];
    float* out = (float*)d_out;

    const int B = 4, S = 2048, D = 2048, H = 16, Dh = 128;
    const int M = B * S;
    const size_t elems  = (size_t)M * D;   // 16,777,216
    const size_t welems = (size_t)D * D;   //  4,194,304

    // ws (bf16): Q | K | V(->Ctx) = 100.7 MiB (same footprint as before).
    bf16_t* Qw  = (bf16_t*)d_ws;
    bf16_t* Kw  = Qw + elems;
    bf16_t* Vw  = Kw + elems;
    bf16_t* Ctx = Vw;
    bf16_t* wob = Qw;            // reuse Q region after flash_attn

    // d_out (67 MiB fp32) hosts transient bf16 data, all dead before the
    // final GEMM writes it:
    //  phase 1: xb [0,33.5MiB) | wqb/wkb/wvb [33.5,58.7MiB)
    //  phase 2: Vt  [0,33.5MiB)  (xb dead after QKV GEMMs)
    bf16_t* outb = (bf16_t*)d_out;
    bf16_t* xb   = outb;
    bf16_t* wqb  = outb + elems;
    bf16_t* wkb  = wqb + welems;
    bf16_t* wvb  = wkb + welems;
    bf16_t* Vtw  = outb;

    cvt_f32_bf16<<<2048, 256, 0, stream>>>(x,  xb,  (int)(elems / 8));
    cvt_f32_bf16<<<2048, 256, 0, stream>>>(wq, wqb, (int)(welems / 8));
    cvt_f32_bf16<<<2048, 256, 0, stream>>>(wk, wkb, (int)(welems / 8));
    cvt_f32_bf16<<<2048, 256, 0, stream>>>(wv, wvb, (int)(welems / 8));

    dim3 gGemm(M / 128, D / 128);
    gemm_bt_lds<bf16_t><<<gGemm, 256, 0, stream>>>(xb, wqb, bq, Qw, M, D, D);
    gemm_bt_lds<bf16_t><<<gGemm, 256, 0, stream>>>(xb, wkb, bk, Kw, M, D, D);
    gemm_bt_lds<bf16_t><<<gGemm, 256, 0, stream>>>(xb, wvb, bv, Vw, M, D, D);

    size_t nrope = (size_t)M * H * 64;
    rope_kernel<<<(int)(nrope / 256), 256, 0, stream>>>(Qw, Kw);

    dim3 gT(S / 64, Dh / 64, B * H);
    transpose_v<<<gT, 256, 0, stream>>>(Vw, Vtw);

    dim3 gA(S / 64, B * H);
    flash_attn<<<gA, 256, 0, stream>>>(Qw, Kw, Vtw, Ctx);

    cvt_f32_bf16<<<2048, 256, 0, stream>>>(wo, wob, (int)(welems / 8));
    gemm_bt_lds<float><<<gGemm, 256, 0, stream>>>(Ctx, wob, bo, out, M, D, D);
}

// Round 3
// 922.958 us; speedup vs baseline: 1.2826x; 1.0124x over previous
//
#include <hip/hip_runtime.h>
#include <hip/hip_bf16.h>

typedef __bf16 bf16_t;
typedef __bf16 bf16x8 __attribute__((ext_vector_type(8)));
typedef float f32x4 __attribute__((ext_vector_type(4)));

#define MFMA16(A, B, C) __builtin_amdgcn_mfma_f32_16x16x32_bf16(A, B, C, 0, 0, 0)

// Async global->LDS, 16B per lane. LDS dest is wave-uniform base + lane*16.
#define GLOAD_LDS16(gp, lp)                                           \
    __builtin_amdgcn_global_load_lds(                                 \
        (const __attribute__((address_space(1))) void*)(gp),          \
        (__attribute__((address_space(3))) void*)(lp), 16, 0, 0)

__device__ __forceinline__ uint32_t pack2(bf16_t a, bf16_t b) {
    union { bf16_t h[2]; uint32_t u; } x;
    x.h[0] = a; x.h[1] = b;
    return x.u;
}

// ---------------------------------------------------------------------------
// fp32 -> bf16 elementwise convert, 8 elems/thread, grid-stride.
// ---------------------------------------------------------------------------
__global__ __launch_bounds__(256)
void cvt_f32_bf16(const float* __restrict__ src, bf16_t* __restrict__ dst, int n8)
{
    int stride = gridDim.x * 256;
    for (int i = blockIdx.x * 256 + threadIdx.x; i < n8; i += stride) {
        const float4 f0 = *(const float4*)(src + (size_t)i * 8);
        const float4 f1 = *(const float4*)(src + (size_t)i * 8 + 4);
        bf16x8 v = {(bf16_t)f0.x, (bf16_t)f0.y, (bf16_t)f0.z, (bf16_t)f0.w,
                    (bf16_t)f1.x, (bf16_t)f1.y, (bf16_t)f1.z, (bf16_t)f1.w};
        *(bf16x8*)(dst + (size_t)i * 8) = v;
    }
}

// ---------------------------------------------------------------------------
// GEMM: C[M,N] = A[M,K] @ W[N,K]^T + bias[N]. A, W bf16; fp32 accum.
// m97 structure: 128x128 tile, BK=32, linear LDS, global_load_lds width=16.
// ---------------------------------------------------------------------------
template <typename OT>
__global__ __launch_bounds__(256)
void gemm_bt_lds(const bf16_t* __restrict__ A, const bf16_t* __restrict__ W,
                 const float* __restrict__ bias, OT* __restrict__ C,
                 int M, int N, int K)
{
    __shared__ __align__(16) bf16_t lds_a[128 * 32];
    __shared__ __align__(16) bf16_t lds_b[128 * 32];

    const int tid  = threadIdx.x;
    const int wave = tid >> 6;
    const int lane = tid & 63;
    const int l15  = lane & 15;
    const int quad = lane >> 4;
    const int wm   = (wave >> 1) * 64;
    const int wn   = (wave & 1) * 64;

    const int bm = blockIdx.x * 128;
    const int bn = blockIdx.y * 128;

    const int srow = wave * 32 + (lane >> 2);
    const int scol = (lane & 3) * 8;

    const bf16_t* Ab = A + (size_t)(bm + srow) * K + scol;
    const bf16_t* Wb = W + (size_t)(bn + srow) * K + scol;
    bf16_t* la0 = &lds_a[wave * 32 * 32];
    bf16_t* lb0 = &lds_b[wave * 32 * 32];

    f32x4 acc[4][4] = {};

    for (int k0 = 0; k0 < K; k0 += 32) {
        GLOAD_LDS16(Ab + k0,          la0);
        GLOAD_LDS16(Ab + k0 + 16 * K, la0 + 16 * 32);
        GLOAD_LDS16(Wb + k0,          lb0);
        GLOAD_LDS16(Wb + k0 + 16 * K, lb0 + 16 * 32);
        __syncthreads();

        bf16x8 af[4], bfr[4];
        for (int i = 0; i < 4; ++i)
            af[i] = *(const bf16x8*)&lds_a[(wm + i * 16 + l15) * 32 + quad * 8];
        for (int j = 0; j < 4; ++j)
            bfr[j] = *(const bf16x8*)&lds_b[(wn + j * 16 + l15) * 32 + quad * 8];
        for (int i = 0; i < 4; ++i)
            for (int j = 0; j < 4; ++j)
                acc[i][j] = MFMA16(af[i], bfr[j], acc[i][j]);
        __syncthreads();
    }

    for (int i = 0; i < 4; ++i) {
        int mrow = bm + wm + i * 16 + quad * 4;
        for (int j = 0; j < 4; ++j) {
            int ncol = bn + wn + j * 16 + l15;
            float bval = bias[ncol];
            for (int r = 0; r < 4; ++r) {
                float v = acc[i][j][r] + bval;
                if constexpr (__is_same(OT, float))
                    C[(size_t)(mrow + r) * N + ncol] = v;
                else
                    C[(size_t)(mrow + r) * N + ncol] = (bf16_t)v;
            }
        }
    }
}

// ---------------------------------------------------------------------------
// RoPE in-place on Q and K (bf16 ws), layout [B*S, H*Dh], pairs (j, j+64).
// ---------------------------------------------------------------------------
__global__ __launch_bounds__(256)
void rope_kernel(bf16_t* __restrict__ Q, bf16_t* __restrict__ Kk)
{
    size_t idx = (size_t)blockIdx.x * 256 + threadIdx.x;
    int j = (int)(idx & 63);
    size_t rest = idx >> 6;
    int h = (int)(rest & 15);
    size_t row = rest >> 4;
    int s = (int)(row & 2047);

    float inv = __expf(-(float)j * 0.14391156831212787f);  // ln(10000)/64
    float ang = (float)s * inv;
    float sn, cs;
    sincosf(ang, &sn, &cs);

    size_t base = row * 2048 + (size_t)h * 128 + j;
    float q0 = (float)Q[base], q1 = (float)Q[base + 64];
    Q[base]      = (bf16_t)(q0 * cs - q1 * sn);
    Q[base + 64] = (bf16_t)(q1 * cs + q0 * sn);
    float k0 = (float)Kk[base], k1 = (float)Kk[base + 64];
    Kk[base]      = (bf16_t)(k0 * cs - k1 * sn);
    Kk[base + 64] = (bf16_t)(k1 * cs + k0 * sn);
}

// ---------------------------------------------------------------------------
// Transpose V [B,S,H*Dh] -> Vt [B,H,Dh,S]  (bf16)
// ---------------------------------------------------------------------------
__global__ __launch_bounds__(256)
void transpose_v(const bf16_t* __restrict__ V, bf16_t* __restrict__ Vt)
{
    __shared__ __align__(16) bf16_t tile[64][72];
    int bh = blockIdx.z;
    int b = bh >> 4, h = bh & 15;
    int t0 = blockIdx.x * 64;
    int d0 = blockIdx.y * 64;
    int tid = threadIdx.x;

    for (int i = 0; i < 2; ++i) {
        int c = tid + i * 256;
        int row = c >> 3, col = (c & 7) * 8;
        *(uint4*)&tile[row][col] =
            *(const uint4*)&V[((size_t)(b * 2048 + t0 + row)) * 2048 + h * 128 + d0 + col];
    }
    __syncthreads();
    for (int i = 0; i < 2; ++i) {
        int c = tid + i * 256;
        int drow = c >> 3, tcol = (c & 7) * 8;
        __align__(16) bf16_t tmp[8];
        for (int j = 0; j < 8; ++j) tmp[j] = tile[tcol + j][drow];
        *(uint4*)&Vt[((size_t)((b * 16 + h) * 128 + d0 + drow)) * 2048 + t0 + tcol] =
            *(uint4*)tmp;
    }
}

// ---------------------------------------------------------------------------
// Flash attention v2: swapped QK^T (ST = K x Q) -> in-register softmax via
// 4-lane-group shfl_xor; swapped PV (O^T = Vt x P^T) so alpha/1/l are
// lane-local. XOR-swizzled K/V LDS tiles (T2). KVBLK=64, 32 q-rows/wave
// (2 fragment groups share every K/V ds_read). 2 barriers per KV tile.
// ---------------------------------------------------------------------------
__global__ __launch_bounds__(256)
void flash_attn(const bf16_t* __restrict__ Q, const bf16_t* __restrict__ Kg,
                const bf16_t* __restrict__ Vt, bf16_t* __restrict__ Ctx)
{
    constexpr int S = 2048, H = 16, Dh = 128, D = 2048;
    constexpr float scale = 0.08838834764831845f;  // 1/sqrt(128)

    // Q staging [128][136] (prologue only) aliases K [64][128] + Vt [128][64].
    __shared__ __align__(16) char smem[128 * 136 * 2];
    bf16_t* qst  = (bf16_t*)smem;
    char* k_raw  = smem;          // [64][128] bf16, swizzled, 16384 B
    char* vt_raw = smem + 16384;  // [128][64] bf16, swizzled, 16384 B

    const int bh = blockIdx.y;
    const int b = bh >> 4, h = bh & 15;
    const int q0 = blockIdx.x * 128;
    const int tid = threadIdx.x, wave = tid >> 6, lane = tid & 63;
    const int l15 = lane & 15, quad = lane >> 4;
    const int hi2 = quad >> 1;
    const int swz = (l15 & 7) << 4;

    const bf16_t* Qh  = Q  + ((size_t)b * S) * D + h * Dh;
    const bf16_t* Kh  = Kg + ((size_t)b * S) * D + h * Dh;
    const bf16_t* Vth = Vt + ((size_t)(b * H + h)) * Dh * S;

    // ---- prologue: stage Q tile [128 rows][128 cols], pull fragments.
    for (int i = 0; i < 8; ++i) {
        int c = tid + i * 256;
        int row = c >> 4, col = (c & 15) * 8;
        *(uint4*)&qst[row * 136 + col] =
            *(const uint4*)&Qh[(size_t)(q0 + row) * D + col];
    }
    __syncthreads();
    bf16x8 aq[2][4];   // B-operand frags: q rows wave*32 + g*16 + l15
    for (int g = 0; g < 2; ++g)
        for (int ks = 0; ks < 4; ++ks)
            aq[g][ks] = *(const bf16x8*)
                &qst[(wave * 32 + g * 16 + l15) * 136 + ks * 32 + quad * 8];
    __syncthreads();  // Q reads done before smem is reused for K/V

    float m_i[2] = {-3.0e4f, -3.0e4f};
    float l_i[2] = {0.f, 0.f};
    f32x4 ot[2][8] = {};   // O^T[d=16j+4quad+r][q=l15] per group

    for (int kt = 0; kt < S / 64; ++kt) {
        // stage K [64][128] swizzled: byte ^= (row&7)<<4
        for (int i = 0; i < 4; ++i) {
            int c = tid + i * 256;
            int row = c >> 4, slot = c & 15;
            int dst = (row * 256 + slot * 16) ^ ((row & 7) << 4);
            *(uint4*)(k_raw + dst) =
                *(const uint4*)&Kh[(size_t)(kt * 64 + row) * D + slot * 8];
        }
        // stage Vt [128][64] swizzled
        for (int i = 0; i < 4; ++i) {
            int c = tid + i * 256;
            int row = c >> 3, slot = c & 7;
            int dst = (row * 128 + slot * 16) ^ ((row & 7) << 4);
            *(uint4*)(vt_raw + dst) =
                *(const uint4*)&Vth[(size_t)row * S + kt * 64 + slot * 8];
        }
        __syncthreads();

        // QK^T swapped: st[g][kvs][r] = S[q=l15][kv = 16*kvs + 4*quad + r]
        f32x4 st[2][4] = {};
        for (int ks = 0; ks < 4; ++ks)
            for (int kvs = 0; kvs < 4; ++kvs) {
                int row = kvs * 16 + l15;
                int off = (row * 256 + ks * 64 + quad * 16) ^ swz;
                bf16x8 kf = *(const bf16x8*)(k_raw + off);
                st[0][kvs] = MFMA16(kf, aq[0][ks], st[0][kvs]);
                st[1][kvs] = MFMA16(kf, aq[1][ks], st[1][kvs]);
            }

        bf16x8 pb[2][2];
        for (int g = 0; g < 2; ++g) {
            // row-max over the 64-kv tile: 15 local fmax + 2 shfl_xor
            float pm = -3.0e4f;
            for (int kvs = 0; kvs < 4; ++kvs)
                for (int r = 0; r < 4; ++r) pm = fmaxf(pm, st[g][kvs][r]);
            pm = fmaxf(pm, __shfl_xor(pm, 16));
            pm = fmaxf(pm, __shfl_xor(pm, 32));
            pm *= scale;

            // defer-max (T13): skip O-rescale when max growth <= 8
            if (!__all(pm - m_i[g] <= 8.0f)) {
                float mnew  = fmaxf(m_i[g], pm);
                float alpha = __expf(m_i[g] - mnew);
                for (int j = 0; j < 8; ++j) ot[g][j] *= alpha;
                l_i[g] *= alpha;
                m_i[g] = mnew;
            }

            // P = exp(s*scale - m); quantize to bf16; sum quantized values
            uint32_t u[4][2];
            float ps = 0.f;
            for (int kvs = 0; kvs < 4; ++kvs) {
                bf16_t hq[4];
                for (int r = 0; r < 4; ++r) {
                    float pf = __expf(fmaf(st[g][kvs][r], scale, -m_i[g]));
                    hq[r] = (bf16_t)pf;
                    ps += (float)hq[r];
                }
                u[kvs][0] = pack2(hq[0], hq[1]);
                u[kvs][1] = pack2(hq[2], hq[3]);
            }
            ps += __shfl_xor(ps, 16);
            ps += __shfl_xor(ps, 32);
            l_i[g] += ps;

            // exchange D-layout P -> B-fragment layout:
            // need elem e of pb[kk] = P[l15][32kk + 8quad + e]
            int srcA = (quad & 1) * 32 + l15;
            int srcB = srcA + 16;
            for (int kk = 0; kk < 2; ++kk) {
                uint32_t a00 = __shfl((int)u[2 * kk + 0][0], srcA);
                uint32_t a01 = __shfl((int)u[2 * kk + 0][1], srcA);
                uint32_t a10 = __shfl((int)u[2 * kk + 1][0], srcA);
                uint32_t a11 = __shfl((int)u[2 * kk + 1][1], srcA);
                uint32_t b00 = __shfl((int)u[2 * kk + 0][0], srcB);
                uint32_t b01 = __shfl((int)u[2 * kk + 0][1], srcB);
                uint32_t b10 = __shfl((int)u[2 * kk + 1][0], srcB);
                uint32_t b11 = __shfl((int)u[2 * kk + 1][1], srcB);
                union { uint32_t w[4]; bf16x8 v; } cc;
                cc.w[0] = hi2 ? a10 : a00;
                cc.w[1] = hi2 ? a11 : a01;
                cc.w[2] = hi2 ? b10 : b00;
                cc.w[3] = hi2 ? b11 : b01;
                pb[g][kk] = cc.v;
            }
        }

        // PV swapped: each Vt read feeds both groups
        for (int j = 0; j < 8; ++j)
            for (int kk = 0; kk < 2; ++kk) {
                int row = j * 16 + l15;
                int off = (row * 128 + kk * 64 + quad * 16) ^ swz;
                bf16x8 av = *(const bf16x8*)(vt_raw + off);
                ot[0][j] = MFMA16(av, pb[0][kk], ot[0][j]);
                ot[1][j] = MFMA16(av, pb[1][kk], ot[1][j]);
            }
        __syncthreads();
    }

    // epilogue: 1/l is lane-local; regs r are contiguous d -> 8B stores
    for (int g = 0; g < 2; ++g) {
        float linv = 1.0f / l_i[g];
        size_t row = (size_t)b * S + q0 + wave * 32 + g * 16 + l15;
        for (int j = 0; j < 8; ++j) {
            union { bf16_t hh[4]; uint2 uu; } o;
            for (int r = 0; r < 4; ++r) o.hh[r] = (bf16_t)(ot[g][j][r] * linv);
            *(uint2*)&Ctx[row * D + h * Dh + j * 16 + quad * 4] = o.uu;
        }
    }
}

// ---------------------------------------------------------------------------
extern "C" void kernel_launch(void* const* d_in, const int* in_sizes, int n_in,
                              void* d_out, int out_size, void* d_ws, size_t ws_size,
                              hipStream_t stream)
{
    const float* x  = (const float*)d_in[0];
    const float* wq = (const float*)d_in[1];
    const float* bq = (const float*)d_in[2];
    const float* wk = (const float*)d_in[3];
    const float* bk = (const float*)d_in[4];
    const float* wv = (const float*)d_in[5];
    const float* bv = (const float*)d_in[6];
    const float* wo = (const float*)d_in[7];
    const float* bo = (const float*)d_in[8];
    float* out = (float*)d_out;

    const int B = 4, S = 2048, D = 2048, H = 16, Dh = 128;
    const int M = B * S;
    const size_t elems  = (size_t)M * D;   // 16,777,216
    const size_t welems = (size_t)D * D;   //  4,194,304

    // ws (bf16): Q | K | V(->Ctx) = 100.7 MiB.
    bf16_t* Qw  = (bf16_t*)d_ws;
    bf16_t* Kw  = Qw + elems;
    bf16_t* Vw  = Kw + elems;
    bf16_t* Ctx = Vw;
    bf16_t* wob = Qw;            // reuse Q region after flash_attn

    // d_out hosts transient bf16 data, dead before the final GEMM writes it.
    bf16_t* outb = (bf16_t*)d_out;
    bf16_t* xb   = outb;
    bf16_t* wqb  = outb + elems;
    bf16_t* wkb  = wqb + welems;
    bf16_t* wvb  = wkb + welems;
    bf16_t* Vtw  = outb;

    cvt_f32_bf16<<<2048, 256, 0, stream>>>(x,  xb,  (int)(elems / 8));
    cvt_f32_bf16<<<2048, 256, 0, stream>>>(wq, wqb, (int)(welems / 8));
    cvt_f32_bf16<<<2048, 256, 0, stream>>>(wk, wkb, (int)(welems / 8));
    cvt_f32_bf16<<<2048, 256, 0, stream>>>(wv, wvb, (int)(welems / 8));

    dim3 gGemm(M / 128, D / 128);
    gemm_bt_lds<bf16_t><<<gGemm, 256, 0, stream>>>(xb, wqb, bq, Qw, M, D, D);
    gemm_bt_lds<bf16_t><<<gGemm, 256, 0, stream>>>(xb, wkb, bk, Kw, M, D, D);
    gemm_bt_lds<bf16_t><<<gGemm, 256, 0, stream>>>(xb, wvb, bv, Vw, M, D, D);

    size_t nrope = (size_t)M * H * 64;
    rope_kernel<<<(int)(nrope / 256), 256, 0, stream>>>(Qw, Kw);

    dim3 gT(S / 64, Dh / 64, B * H);
    transpose_v<<<gT, 256, 0, stream>>>(Vw, Vtw);

    dim3 gA(S / 128, B * H);
    flash_attn<<<gA, 256, 0, stream>>>(Qw, Kw, Vtw, Ctx);

    cvt_f32_bf16<<<2048, 256, 0, stream>>>(wo, wob, (int)(welems / 8));
    gemm_bt_lds<float><<<gGemm, 256, 0, stream>>>(Ctx, wob, bo, out, M, D, D);
}

// Round 4
// 791.718 us; speedup vs baseline: 1.4952x; 1.1658x over previous
//
#include <hip/hip_runtime.h>
#include <hip/hip_bf16.h>

typedef __bf16 bf16_t;
typedef __bf16 bf16x8 __attribute__((ext_vector_type(8)));
typedef float f32x4 __attribute__((ext_vector_type(4)));

#define MFMA16(A, B, C) __builtin_amdgcn_mfma_f32_16x16x32_bf16(A, B, C, 0, 0, 0)

// Async global->LDS, 16B per lane. LDS dest is wave-uniform base + lane*16;
// global source is per-lane (pre-swizzle swizzled layouts on the source).
#define GLOAD_LDS16(gp, lp)                                           \
    __builtin_amdgcn_global_load_lds(                                 \
        (const __attribute__((address_space(1))) void*)(gp),          \
        (__attribute__((address_space(3))) void*)(lp), 16, 0, 0)

__device__ __forceinline__ uint32_t pack2(bf16_t a, bf16_t b) {
    union { bf16_t h[2]; uint32_t u; } x;
    x.h[0] = a; x.h[1] = b;
    return x.u;
}

// ---------------------------------------------------------------------------
// fp32 -> bf16 elementwise convert, 8 elems/thread, grid-stride.
// ---------------------------------------------------------------------------
__global__ __launch_bounds__(256)
void cvt_f32_bf16(const float* __restrict__ src, bf16_t* __restrict__ dst, int n8)
{
    int stride = gridDim.x * 256;
    for (int i = blockIdx.x * 256 + threadIdx.x; i < n8; i += stride) {
        const float4 f0 = *(const float4*)(src + (size_t)i * 8);
        const float4 f1 = *(const float4*)(src + (size_t)i * 8 + 4);
        bf16x8 v = {(bf16_t)f0.x, (bf16_t)f0.y, (bf16_t)f0.z, (bf16_t)f0.w,
                    (bf16_t)f1.x, (bf16_t)f1.y, (bf16_t)f1.z, (bf16_t)f1.w};
        *(bf16x8*)(dst + (size_t)i * 8) = v;
    }
}

// ---------------------------------------------------------------------------
// GEMM: C[M,N] = A[M,K] @ W[N,K]^T + bias[N]. A, W bf16; fp32 accum.
// m97 structure: 128x128 tile, BK=32, linear LDS, global_load_lds width=16.
// ---------------------------------------------------------------------------
template <typename OT>
__global__ __launch_bounds__(256)
void gemm_bt_lds(const bf16_t* __restrict__ A, const bf16_t* __restrict__ W,
                 const float* __restrict__ bias, OT* __restrict__ C,
                 int M, int N, int K)
{
    __shared__ __align__(16) bf16_t lds_a[128 * 32];
    __shared__ __align__(16) bf16_t lds_b[128 * 32];

    const int tid  = threadIdx.x;
    const int wave = tid >> 6;
    const int lane = tid & 63;
    const int l15  = lane & 15;
    const int quad = lane >> 4;
    const int wm   = (wave >> 1) * 64;
    const int wn   = (wave & 1) * 64;

    const int bm = blockIdx.x * 128;
    const int bn = blockIdx.y * 128;

    const int srow = wave * 32 + (lane >> 2);
    const int scol = (lane & 3) * 8;

    const bf16_t* Ab = A + (size_t)(bm + srow) * K + scol;
    const bf16_t* Wb = W + (size_t)(bn + srow) * K + scol;
    bf16_t* la0 = &lds_a[wave * 32 * 32];
    bf16_t* lb0 = &lds_b[wave * 32 * 32];

    f32x4 acc[4][4] = {};

    for (int k0 = 0; k0 < K; k0 += 32) {
        GLOAD_LDS16(Ab + k0,          la0);
        GLOAD_LDS16(Ab + k0 + 16 * K, la0 + 16 * 32);
        GLOAD_LDS16(Wb + k0,          lb0);
        GLOAD_LDS16(Wb + k0 + 16 * K, lb0 + 16 * 32);
        __syncthreads();

        bf16x8 af[4], bfr[4];
        for (int i = 0; i < 4; ++i)
            af[i] = *(const bf16x8*)&lds_a[(wm + i * 16 + l15) * 32 + quad * 8];
        for (int j = 0; j < 4; ++j)
            bfr[j] = *(const bf16x8*)&lds_b[(wn + j * 16 + l15) * 32 + quad * 8];
        for (int i = 0; i < 4; ++i)
            for (int j = 0; j < 4; ++j)
                acc[i][j] = MFMA16(af[i], bfr[j], acc[i][j]);
        __syncthreads();
    }

    for (int i = 0; i < 4; ++i) {
        int mrow = bm + wm + i * 16 + quad * 4;
        for (int j = 0; j < 4; ++j) {
            int ncol = bn + wn + j * 16 + l15;
            float bval = bias[ncol];
            for (int r = 0; r < 4; ++r) {
                float v = acc[i][j][r] + bval;
                if constexpr (__is_same(OT, float))
                    C[(size_t)(mrow + r) * N + ncol] = v;
                else
                    C[(size_t)(mrow + r) * N + ncol] = (bf16_t)v;
            }
        }
    }
}

// ---------------------------------------------------------------------------
// RoPE in-place on Q and K (bf16 ws), layout [B*S, H*Dh], pairs (j, j+64).
// ---------------------------------------------------------------------------
__global__ __launch_bounds__(256)
void rope_kernel(bf16_t* __restrict__ Q, bf16_t* __restrict__ Kk)
{
    size_t idx = (size_t)blockIdx.x * 256 + threadIdx.x;
    int j = (int)(idx & 63);
    size_t rest = idx >> 6;
    int h = (int)(rest & 15);
    size_t row = rest >> 4;
    int s = (int)(row & 2047);

    float inv = __expf(-(float)j * 0.14391156831212787f);  // ln(10000)/64
    float ang = (float)s * inv;
    float sn, cs;
    sincosf(ang, &sn, &cs);

    size_t base = row * 2048 + (size_t)h * 128 + j;
    float q0 = (float)Q[base], q1 = (float)Q[base + 64];
    Q[base]      = (bf16_t)(q0 * cs - q1 * sn);
    Q[base + 64] = (bf16_t)(q1 * cs + q0 * sn);
    float k0 = (float)Kk[base], k1 = (float)Kk[base + 64];
    Kk[base]      = (bf16_t)(k0 * cs - k1 * sn);
    Kk[base + 64] = (bf16_t)(k1 * cs + k0 * sn);
}

// ---------------------------------------------------------------------------
// Transpose V [B,S,H*Dh] -> Vt [B,H,Dh,S]  (bf16)
// ---------------------------------------------------------------------------
__global__ __launch_bounds__(256)
void transpose_v(const bf16_t* __restrict__ V, bf16_t* __restrict__ Vt)
{
    __shared__ __align__(16) bf16_t tile[64][72];
    int bh = blockIdx.z;
    int b = bh >> 4, h = bh & 15;
    int t0 = blockIdx.x * 64;
    int d0 = blockIdx.y * 64;
    int tid = threadIdx.x;

    for (int i = 0; i < 2; ++i) {
        int c = tid + i * 256;
        int row = c >> 3, col = (c & 7) * 8;
        *(uint4*)&tile[row][col] =
            *(const uint4*)&V[((size_t)(b * 2048 + t0 + row)) * 2048 + h * 128 + d0 + col];
    }
    __syncthreads();
    for (int i = 0; i < 2; ++i) {
        int c = tid + i * 256;
        int drow = c >> 3, tcol = (c & 7) * 8;
        __align__(16) bf16_t tmp[8];
        for (int j = 0; j < 8; ++j) tmp[j] = tile[tcol + j][drow];
        *(uint4*)&Vt[((size_t)((b * 16 + h) * 128 + d0 + drow)) * 2048 + t0 + tcol] =
            *(uint4*)tmp;
    }
}

// ---------------------------------------------------------------------------
// Flash attention v3: v2's swapped QK^T / in-register softmax / swapped PV,
// plus: (a) K/V staging via global_load_lds with PRE-SWIZZLED per-lane global
// source (LDS dest linear; content lands XOR-swizzled) -- frees the staging
// VGPRs; (b) double-buffered K/V (2x32KB) with the 2-phase recipe: issue
// next-tile STAGE before computing current tile, one barrier per tile;
// (c) __launch_bounds__(256,2) to guarantee 2 waves/SIMD; (d) s_setprio
// around MFMA clusters.
// ---------------------------------------------------------------------------
__global__ __launch_bounds__(256, 2)
void flash_attn(const bf16_t* __restrict__ Q, const bf16_t* __restrict__ Kg,
                const bf16_t* __restrict__ Vt, bf16_t* __restrict__ Ctx)
{
    constexpr int S = 2048, H = 16, Dh = 128, D = 2048;
    constexpr int NT = S / 64;
    constexpr float scale = 0.08838834764831845f;  // 1/sqrt(128)

    // Double buffer: buf c at smem + c*32768 = [K 16KB | Vt 16KB].
    // Q prologue staging [128][136] (34816 B) aliases the front of smem.
    __shared__ __align__(16) char smem[65536];
    bf16_t* qst = (bf16_t*)smem;

    const int bh = blockIdx.y;
    const int b = bh >> 4, h = bh & 15;
    const int q0 = blockIdx.x * 128;
    const int tid = threadIdx.x, wave = tid >> 6, lane = tid & 63;
    const int l15 = lane & 15, quad = lane >> 4;
    const int hi2 = quad >> 1;
    const int swz = (l15 & 7) << 4;

    const bf16_t* Qh  = Q  + ((size_t)b * S) * D + h * Dh;
    const bf16_t* Kh  = Kg + ((size_t)b * S) * D + h * Dh;
    const bf16_t* Vth = Vt + ((size_t)(b * H + h)) * Dh * S;

    // Pre-swizzled per-lane source offsets (constant over kt).
    // K LDS linear layout: byte L -> row=L>>8, s_lin=(L>>4)&15; content must be
    // global (row, slot = s_lin ^ (row&7)). One gload_lds = 1KB = 4 K-rows.
    // V LDS linear: byte L -> row=L>>7, s_lin=(L>>4)&7; 1KB = 8 Vt-rows.
    int ks_off[4], vs_off[4];
#pragma unroll
    for (int i = 0; i < 4; ++i) {
        int kr = wave * 16 + i * 4 + (lane >> 4);
        int ksl = lane & 15;
        ks_off[i] = kr * D + ((ksl ^ (kr & 7)) * 8);
        int vr = wave * 32 + i * 8 + (lane >> 3);
        int vsl = lane & 7;
        vs_off[i] = vr * S + ((vsl ^ (vr & 7)) * 8);
    }

    // ---- prologue: stage Q tile [128 rows][128 cols], pull fragments.
    for (int i = 0; i < 8; ++i) {
        int c = tid + i * 256;
        int row = c >> 4, col = (c & 15) * 8;
        *(uint4*)&qst[row * 136 + col] =
            *(const uint4*)&Qh[(size_t)(q0 + row) * D + col];
    }
    __syncthreads();
    bf16x8 aq[2][4];   // B-operand frags: q rows wave*32 + g*16 + l15
    for (int g = 0; g < 2; ++g)
        for (int ks = 0; ks < 4; ++ks)
            aq[g][ks] = *(const bf16x8*)
                &qst[(wave * 32 + g * 16 + l15) * 136 + ks * 32 + quad * 8];
    __syncthreads();  // Q reads done before smem is reused for K/V

    float m_i[2] = {-3.0e4f, -3.0e4f};
    float l_i[2] = {0.f, 0.f};
    f32x4 ot[2][8] = {};   // O^T[d=16j+4quad+r][q=l15] per group

    // Stage tile 0 into buffer 0.
    {
        char* kb = smem;
        char* vb = smem + 16384;
        const bf16_t* Vs = Vth;
#pragma unroll
        for (int i = 0; i < 4; ++i) {
            GLOAD_LDS16(Kh + ks_off[i], kb + wave * 4096 + i * 1024);
            GLOAD_LDS16(Vs + vs_off[i], vb + wave * 4096 + i * 1024);
        }
    }
    __syncthreads();  // drains vmcnt -> buf0 ready

    for (int kt = 0; kt < NT; ++kt) {
        const int cur = kt & 1;
        // Issue next-tile staging first; latency hides under this tile's math.
        if (kt + 1 < NT) {
            char* kb = smem + (cur ^ 1) * 32768;
            char* vb = kb + 16384;
            const bf16_t* Ks = Kh + (size_t)(kt + 1) * 64 * D;
            const bf16_t* Vs = Vth + (kt + 1) * 64;
#pragma unroll
            for (int i = 0; i < 4; ++i) {
                GLOAD_LDS16(Ks + ks_off[i], kb + wave * 4096 + i * 1024);
                GLOAD_LDS16(Vs + vs_off[i], vb + wave * 4096 + i * 1024);
            }
        }
        const char* k_raw  = smem + cur * 32768;
        const char* vt_raw = k_raw + 16384;

        // QK^T swapped: st[g][kvs][r] = S[q=l15][kv = 16*kvs + 4*quad + r]
        f32x4 st[2][4] = {};
        __builtin_amdgcn_s_setprio(1);
        for (int ks = 0; ks < 4; ++ks)
            for (int kvs = 0; kvs < 4; ++kvs) {
                int row = kvs * 16 + l15;
                int off = (row * 256 + ks * 64 + quad * 16) ^ swz;
                bf16x8 kf = *(const bf16x8*)(k_raw + off);
                st[0][kvs] = MFMA16(kf, aq[0][ks], st[0][kvs]);
                st[1][kvs] = MFMA16(kf, aq[1][ks], st[1][kvs]);
            }
        __builtin_amdgcn_s_setprio(0);

        bf16x8 pb[2][2];
        for (int g = 0; g < 2; ++g) {
            // row-max over the 64-kv tile: 15 local fmax + 2 shfl_xor
            float pm = -3.0e4f;
            for (int kvs = 0; kvs < 4; ++kvs)
                for (int r = 0; r < 4; ++r) pm = fmaxf(pm, st[g][kvs][r]);
            pm = fmaxf(pm, __shfl_xor(pm, 16));
            pm = fmaxf(pm, __shfl_xor(pm, 32));
            pm *= scale;

            // defer-max (T13): skip O-rescale when max growth <= 8
            if (!__all(pm - m_i[g] <= 8.0f)) {
                float mnew  = fmaxf(m_i[g], pm);
                float alpha = __expf(m_i[g] - mnew);
                for (int j = 0; j < 8; ++j) ot[g][j] *= alpha;
                l_i[g] *= alpha;
                m_i[g] = mnew;
            }

            // P = exp(s*scale - m); quantize to bf16; sum quantized values
            uint32_t u[4][2];
            float ps = 0.f;
            for (int kvs = 0; kvs < 4; ++kvs) {
                bf16_t hq[4];
                for (int r = 0; r < 4; ++r) {
                    float pf = __expf(fmaf(st[g][kvs][r], scale, -m_i[g]));
                    hq[r] = (bf16_t)pf;
                    ps += (float)hq[r];
                }
                u[kvs][0] = pack2(hq[0], hq[1]);
                u[kvs][1] = pack2(hq[2], hq[3]);
            }
            ps += __shfl_xor(ps, 16);
            ps += __shfl_xor(ps, 32);
            l_i[g] += ps;

            // exchange D-layout P -> B-fragment layout:
            // need elem e of pb[kk] = P[l15][32kk + 8quad + e]
            int srcA = (quad & 1) * 32 + l15;
            int srcB = srcA + 16;
            for (int kk = 0; kk < 2; ++kk) {
                uint32_t a00 = __shfl((int)u[2 * kk + 0][0], srcA);
                uint32_t a01 = __shfl((int)u[2 * kk + 0][1], srcA);
                uint32_t a10 = __shfl((int)u[2 * kk + 1][0], srcA);
                uint32_t a11 = __shfl((int)u[2 * kk + 1][1], srcA);
                uint32_t b00 = __shfl((int)u[2 * kk + 0][0], srcB);
                uint32_t b01 = __shfl((int)u[2 * kk + 0][1], srcB);
                uint32_t b10 = __shfl((int)u[2 * kk + 1][0], srcB);
                uint32_t b11 = __shfl((int)u[2 * kk + 1][1], srcB);
                union { uint32_t w[4]; bf16x8 v; } cc;
                cc.w[0] = hi2 ? a10 : a00;
                cc.w[1] = hi2 ? a11 : a01;
                cc.w[2] = hi2 ? b10 : b00;
                cc.w[3] = hi2 ? b11 : b01;
                pb[g][kk] = cc.v;
            }
        }

        // PV swapped: each Vt read feeds both groups
        __builtin_amdgcn_s_setprio(1);
        for (int j = 0; j < 8; ++j)
            for (int kk = 0; kk < 2; ++kk) {
                int row = j * 16 + l15;
                int off = (row * 128 + kk * 64 + quad * 16) ^ swz;
                bf16x8 av = *(const bf16x8*)(vt_raw + off);
                ot[0][j] = MFMA16(av, pb[0][kk], ot[0][j]);
                ot[1][j] = MFMA16(av, pb[1][kk], ot[1][j]);
            }
        __builtin_amdgcn_s_setprio(0);

        // One barrier per tile: orders (i) everyone done reading buf[cur]
        // before next iter's STAGE overwrites it, (ii) vmcnt(0) drain means
        // this wave's gload_lds writes to buf[cur^1] have landed.
        __syncthreads();
    }

    // epilogue: 1/l is lane-local; regs r are contiguous d -> 8B stores
    for (int g = 0; g < 2; ++g) {
        float linv = 1.0f / l_i[g];
        size_t row = (size_t)b * S + q0 + wave * 32 + g * 16 + l15;
        for (int j = 0; j < 8; ++j) {
            union { bf16_t hh[4]; uint2 uu; } o;
            for (int r = 0; r < 4; ++r) o.hh[r] = (bf16_t)(ot[g][j][r] * linv);
            *(uint2*)&Ctx[row * D + h * Dh + j * 16 + quad * 4] = o.uu;
        }
    }
}

// ---------------------------------------------------------------------------
extern "C" void kernel_launch(void* const* d_in, const int* in_sizes, int n_in,
                              void* d_out, int out_size, void* d_ws, size_t ws_size,
                              hipStream_t stream)
{
    const float* x  = (const float*)d_in[0];
    const float* wq = (const float*)d_in[1];
    const float* bq = (const float*)d_in[2];
    const float* wk = (const float*)d_in[3];
    const float* bk = (const float*)d_in[4];
    const float* wv = (const float*)d_in[5];
    const float* bv = (const float*)d_in[6];
    const float* wo = (const float*)d_in[7];
    const float* bo = (const float*)d_in[8];
    float* out = (float*)d_out;

    const int B = 4, S = 2048, D = 2048, H = 16, Dh = 128;
    const int M = B * S;
    const size_t elems  = (size_t)M * D;   // 16,777,216
    const size_t welems = (size_t)D * D;   //  4,194,304

    // ws (bf16): Q | K | V(->Ctx) = 100.7 MiB.
    bf16_t* Qw  = (bf16_t*)d_ws;
    bf16_t* Kw  = Qw + elems;
    bf16_t* Vw  = Kw + elems;
    bf16_t* Ctx = Vw;
    bf16_t* wob = Qw;            // reuse Q region after flash_attn

    // d_out hosts transient bf16 data, dead before the final GEMM writes it.
    bf16_t* outb = (bf16_t*)d_out;
    bf16_t* xb   = outb;
    bf16_t* wqb  = outb + elems;
    bf16_t* wkb  = wqb + welems;
    bf16_t* wvb  = wkb + welems;
    bf16_t* Vtw  = outb;

    cvt_f32_bf16<<<2048, 256, 0, stream>>>(x,  xb,  (int)(elems / 8));
    cvt_f32_bf16<<<2048, 256, 0, stream>>>(wq, wqb, (int)(welems / 8));
    cvt_f32_bf16<<<2048, 256, 0, stream>>>(wk, wkb, (int)(welems / 8));
    cvt_f32_bf16<<<2048, 256, 0, stream>>>(wv, wvb, (int)(welems / 8));

    dim3 gGemm(M / 128, D / 128);
    gemm_bt_lds<bf16_t><<<gGemm, 256, 0, stream>>>(xb, wqb, bq, Qw, M, D, D);
    gemm_bt_lds<bf16_t><<<gGemm, 256, 0, stream>>>(xb, wkb, bk, Kw, M, D, D);
    gemm_bt_lds<bf16_t><<<gGemm, 256, 0, stream>>>(xb, wvb, bv, Vw, M, D, D);

    size_t nrope = (size_t)M * H * 64;
    rope_kernel<<<(int)(nrope / 256), 256, 0, stream>>>(Qw, Kw);

    dim3 gT(S / 64, Dh / 64, B * H);
    transpose_v<<<gT, 256, 0, stream>>>(Vw, Vtw);

    dim3 gA(S / 128, B * H);
    flash_attn<<<gA, 256, 0, stream>>>(Qw, Kw, Vtw, Ctx);

    cvt_f32_bf16<<<2048, 256, 0, stream>>>(wo, wob, (int)(welems / 8));
    gemm_bt_lds<float><<<gGemm, 256, 0, stream>>>(Ctx, wob, bo, out, M, D, D);
}